// Round 6
// baseline (3122.019 us; speedup 1.0000x reference)
//
#include <hip/hip_runtime.h>

// ---------------------------------------------------------------------------
// 2-layer tanh RNN, B=64, T=512, I=256, H=512.  Round 6: tag-in-data
// publication (no drain/flag/observe hops), 8-producer domains, LDS weights.
//   - 96 blocks x 256 thr: roles L0(32) / PROJ(32) / L1(32); per role:
//     4 batch-groups x 8 col-blocks(64 cols). Wave = 16 cols, full K.
//   - every cross-block element is a dword (tag16|fp16) in depth-4 rotating
//     slots; producers fire-and-forget relaxed agent stores; consumers use
//     agent-scope (cache-bypassing) loads and retry until every tag matches.
//     Correct under any store reordering; 0xAA poison never aliases a tag.
//   - back-pressure (slot overwrite safety) via monotonic per-wave sentinels,
//     loaded early and __all-checked after compute (off critical path).
//   - weights fp16 in LDS (pitch-padded); staged h in LDS via cooperative
//     coalesced 8B loads -> verify -> pack -> ds_write.
// ---------------------------------------------------------------------------

#define kB 64
#define kT 512
#define kI 256
#define kH 512

#define WP512 528            // 512+16 halves: LDS row pitch (1056 B, 16B-aligned)
#define WP256 272            // 256+16 halves (544 B)
#define SLOTD 8192           // dwords per slot: 16 rows x 512 cols
#define GRPD  32768          // dwords per group: 4 slots

typedef _Float16 half8 __attribute__((ext_vector_type(8)));
typedef _Float16 half4v __attribute__((ext_vector_type(4)));
typedef float floatx4 __attribute__((ext_vector_type(4)));

constexpr size_t X16_B  = 0;                         // [B][T][I] fp16, 16 MB
constexpr size_t OUT0_B = 16u * 1024 * 1024;         // [4g][4slot][16][512] dw
constexpr size_t P1_B   = OUT0_B + (size_t)4 * GRPD * 4;
constexpr size_t H1_B   = P1_B + (size_t)4 * GRPD * 4;
constexpr size_t SENT_B = H1_B + (size_t)4 * GRPD * 4;  // s_proj[4][32], s_l1[4][32]

__device__ inline half8 cvt8(const float* p) {
    const float4* p4 = (const float4*)p;
    float4 a = p4[0], b = p4[1];
    half8 h;
    h[0] = (_Float16)a.x; h[1] = (_Float16)a.y; h[2] = (_Float16)a.z; h[3] = (_Float16)a.w;
    h[4] = (_Float16)b.x; h[5] = (_Float16)b.y; h[6] = (_Float16)b.z; h[7] = (_Float16)b.w;
    return h;
}

__device__ inline int ld_agent(const int* p) {
    return __hip_atomic_load(p, __ATOMIC_RELAXED, __HIP_MEMORY_SCOPE_AGENT);
}
__device__ inline long ld_agent64(const long* p) {
    return __hip_atomic_load(p, __ATOMIC_RELAXED, __HIP_MEMORY_SCOPE_AGENT);
}
__device__ inline void st_agent(int* p, int v) {
    __hip_atomic_store(p, v, __ATOMIC_RELAXED, __HIP_MEMORY_SCOPE_AGENT);
}

__device__ inline float fast_tanh(float s) {
    float e = __expf(2.f * s);
    return 1.f - 2.f / (e + 1.f);
}

// cooperative: load [16][512] tagged dwords from slot, verify every tag,
// strip tags, write packed halves to stage ([16][WP512]).
__device__ inline void stage_rows(const int* slot, unsigned tag,
                                  _Float16* stage, int tid) {
    const long* src = (const long*)slot;   // [16][256] longs
    long v[16];
    unsigned pend = 0xFFFFu;
    int guard = 0;
    while (pend) {
        unsigned np = 0;
#pragma unroll
        for (int p = 0; p < 16; ++p) {
            if (pend & (1u << p)) {
                long x = ld_agent64(src + p * 256 + tid);
                v[p] = x;
                int2 w = __builtin_bit_cast(int2, x);
                if ((((unsigned)w.x >> 16) != tag) || (((unsigned)w.y >> 16) != tag))
                    np |= 1u << p;
            }
        }
        pend = np;
        if (++guard > 2000000) break;   // fail-wrong, not hang
    }
#pragma unroll
    for (int p = 0; p < 16; ++p) {
        int2 w = __builtin_bit_cast(int2, v[p]);
        unsigned packed = __builtin_amdgcn_perm((unsigned)w.y, (unsigned)w.x, 0x05040100u);
        *(unsigned*)((char*)stage + (size_t)p * (WP512 * 2) + (size_t)tid * 4) = packed;
    }
}

__device__ inline void wait_bp(const int* s, int target) {
    const int* p = s + (threadIdx.x & 31);
    int g = 0;
    for (;;) {
        int v = ld_agent(p);
        if (__all(v >= target)) break;
        if (++g > 2000000) break;
    }
}

// load 64 weight rows [row0..row0+64) x K (fp32) into LDS fp16, pitch P
__device__ inline void load_w(const float* W, int row0, int K, int pitch,
                              _Float16* dst, int tid) {
    const int chunks = K / 8;
    for (int idx = tid; idx < 64 * chunks; idx += 256) {
        int row = idx / chunks, ch = idx % chunks;
        *(half8*)(dst + (size_t)row * pitch + ch * 8) =
            cvt8(W + (size_t)(row0 + row) * K + ch * 8);
    }
}

// K=512 MFMA pass: A from stage row r, B from weight row (w*16+r)
__device__ inline void mm512(const _Float16* a, const _Float16* b,
                             floatx4& a0, floatx4& a1) {
#pragma unroll
    for (int m = 0; m < 16; m += 2) {
        half8 av0 = *(const half8*)(a + m * 32);
        half8 bv0 = *(const half8*)(b + m * 32);
        a0 = __builtin_amdgcn_mfma_f32_16x16x32_f16(av0, bv0, a0, 0, 0, 0);
        half8 av1 = *(const half8*)(a + (m + 1) * 32);
        half8 bv1 = *(const half8*)(b + (m + 1) * 32);
        a1 = __builtin_amdgcn_mfma_f32_16x16x32_f16(av1, bv1, a1, 0, 0, 0);
    }
}

__global__ void cvt_x_kernel(const float* __restrict__ x, _Float16* __restrict__ x16) {
    size_t i = ((size_t)blockIdx.x * blockDim.x + threadIdx.x) * 4;
    size_t stride = (size_t)gridDim.x * blockDim.x * 4;
    const size_t n = (size_t)kB * kT * kI;
    for (; i < n; i += stride) {
        float4 v = *(const float4*)(x + i);
        half4v h;
        h[0] = (_Float16)v.x; h[1] = (_Float16)v.y; h[2] = (_Float16)v.z; h[3] = (_Float16)v.w;
        *(half4v*)(x16 + i) = h;
    }
}

// init states into slot 3 with tag 0; zero sentinels
__global__ void setup_kernel(const float* __restrict__ h0, int* __restrict__ out0m,
                             int* __restrict__ h1m, int* __restrict__ sent) {
    int idx = blockIdx.x * blockDim.x + threadIdx.x;   // 0..65535
    int lay = idx >> 15;
    int e = idx & 32767;
    int b = e >> 9, col = e & 511;
    int g = b >> 4, row = b & 15;
    unsigned d = (unsigned)__builtin_bit_cast(unsigned short, (_Float16)h0[idx]);
    int* dst = (lay ? h1m : out0m) + (size_t)g * GRPD + 3 * SLOTD + row * 512 + col;
    *dst = (int)d;                                      // tag 0 in hi16
    if (idx < 256) sent[idx] = 0;
}

__global__ __launch_bounds__(256, 1) void scan_kernel(
    const _Float16* __restrict__ x16, int* __restrict__ out0m,
    int* __restrict__ p1m, int* __restrict__ h1m, int* __restrict__ sent,
    float* __restrict__ out1,
    const float* __restrict__ wih0, const float* __restrict__ whh0,
    const float* __restrict__ bih0, const float* __restrict__ bhh0,
    const float* __restrict__ wih1, const float* __restrict__ whh1,
    const float* __restrict__ bih1, const float* __restrict__ bhh1) {
    __shared__ __align__(16) _Float16 sWa[64 * WP512];   // whh0 / wih1 / whh1
    __shared__ __align__(16) _Float16 sWb[64 * WP256];   // wih0 (L0 only)
    __shared__ __align__(16) _Float16 sStage[16 * WP512];

    const int blk = blockIdx.x;
    const int tid = threadIdx.x;
    const int w = tid >> 6;
    const int lane = tid & 63;
    const int r = lane & 15;         // MFMA A/B row selector
    const int q = lane >> 4;         // MFMA k-subchunk / D-row quad
    const int role = blk >> 5;       // 0=L0, 1=PROJ, 2=L1
    const int sub = blk & 31;
    const int g = sub >> 3;          // batch group
    const int j = sub & 7;           // col block
    const int c0b = j * 64;          // block col base
    const int ccl = c0b + w * 16 + r;            // slab col (== global H col)
    const int* sproj = sent + g * 32;
    const int* sl1 = sent + 128 + g * 32;

    if (role == 0) {
        // ---------------- L0: h0 recurrence (+x projection) ----------------
        load_w(whh0, c0b, 512, WP512, sWa, tid);
        load_w(wih0, c0b, 256, WP256, sWb, tid);
        __syncthreads();
        const float bias = bih0[ccl] + bhh0[ccl];
        int* slabG = out0m + (size_t)g * GRPD;
        const _Float16* bx = sWb + (size_t)(w * 16 + r) * WP256 + q * 8;
        const _Float16* bh = sWa + (size_t)(w * 16 + r) * WP512 + q * 8;

        for (int t = 0; t < kT; ++t) {
            // x projection (independent of the gate)
            const _Float16* xrow = x16 + ((size_t)(g * 16 + r) * kT + t) * kI + q * 8;
            floatx4 ax = {0.f, 0.f, 0.f, 0.f};
#pragma unroll
            for (int m = 0; m < 8; ++m)
                ax = __builtin_amdgcn_mfma_f32_16x16x32_f16(
                    *(const half8*)(xrow + m * 32), *(const half8*)(bx + m * 32), ax, 0, 0, 0);
            // back-pressure prefetch (checked after compute)
            int bpv = ld_agent(sproj + (tid & 31));
            __syncthreads();
            stage_rows(slabG + ((t + 3) & 3) * SLOTD, (unsigned)t, sStage, tid);
            __syncthreads();
            floatx4 a0 = {0.f, 0.f, 0.f, 0.f}, a1 = {0.f, 0.f, 0.f, 0.f};
            mm512(sStage + (size_t)r * WP512 + q * 8, bh, a0, a1);

            int* wslot = slabG + (t & 3) * SLOTD;
            const unsigned tagw = (unsigned)(t + 1) << 16;
#pragma unroll
            for (int i = 0; i < 4; ++i) {
                float v = fast_tanh(ax[i] + a0[i] + a1[i] + bias);
                unsigned hb = (unsigned)__builtin_bit_cast(unsigned short, (_Float16)v);
                st_agent(wslot + (q * 4 + i) * 512 + ccl, (int)(tagw | hb));
            }
            // clear overwrite for step t+1: need s_proj >= (t+1)-3
            if (!__all(bpv >= t - 2)) wait_bp(sproj, t - 2);
        }
    } else if (role == 1) {
        // ---------------- PROJ: p1[t] = out0[t] @ W_ih1^T + bias1 ----------
        load_w(wih1, c0b, 512, WP512, sWa, tid);
        __syncthreads();
        const float bias1 = bih1[ccl] + bhh1[ccl];
        const int* src = out0m + (size_t)g * GRPD;
        int* dst = p1m + (size_t)g * GRPD;
        const _Float16* bw = sWa + (size_t)(w * 16 + r) * WP512 + q * 8;
        const int sidx = g * 32 + j * 4 + w;

        for (int t = 0; t < kT; ++t) {
            int bpv = ld_agent(sl1 + (tid & 31));
            __syncthreads();
            stage_rows(src + (t & 3) * SLOTD, (unsigned)(t + 1), sStage, tid);
            __syncthreads();
            floatx4 a0 = {0.f, 0.f, 0.f, 0.f}, a1 = {0.f, 0.f, 0.f, 0.f};
            mm512(sStage + (size_t)r * WP512 + q * 8, bw, a0, a1);

            int* wslot = dst + (t & 3) * SLOTD;
            const unsigned tagw = (unsigned)(t + 1) << 16;
#pragma unroll
            for (int i = 0; i < 4; ++i) {
                float s = a0[i] + a1[i] + bias1;
                unsigned hb = (unsigned)__builtin_bit_cast(unsigned short, (_Float16)s);
                st_agent(wslot + (q * 4 + i) * 512 + ccl, (int)(tagw | hb));
            }
            if (lane == 0) st_agent((int*)sent + g * 32 + j * 4 + w, t + 1);
            (void)sidx;
            if (!__all(bpv >= t - 2)) wait_bp(sl1, t - 2);
        }
    } else {
        // ---------------- L1: h1 recurrence (+p1 addend) --------------------
        load_w(whh1, c0b, 512, WP512, sWa, tid);
        __syncthreads();
        const int* psrc = p1m + (size_t)g * GRPD;
        int* hG = h1m + (size_t)g * GRPD;
        const _Float16* bw = sWa + (size_t)(w * 16 + r) * WP512 + q * 8;

        for (int t = 0; t < kT; ++t) {
            // p1 first-round loads (verified after staging, overlapped)
            const int* pslot = psrc + (t & 3) * SLOTD;
            int pv[4];
#pragma unroll
            for (int i = 0; i < 4; ++i)
                pv[i] = ld_agent(pslot + (q * 4 + i) * 512 + ccl);
            __syncthreads();
            stage_rows(hG + ((t + 3) & 3) * SLOTD, (unsigned)t, sStage, tid);
            __syncthreads();
            floatx4 a0 = {0.f, 0.f, 0.f, 0.f}, a1 = {0.f, 0.f, 0.f, 0.f};
            mm512(sStage + (size_t)r * WP512 + q * 8, bw, a0, a1);

            // verify p1 tags, retry pending
            const unsigned ptag = (unsigned)(t + 1);
            unsigned pend = 0;
#pragma unroll
            for (int i = 0; i < 4; ++i)
                if (((unsigned)pv[i] >> 16) != ptag) pend |= 1u << i;
            int guard = 0;
            while (pend) {
                unsigned np = 0;
#pragma unroll
                for (int i = 0; i < 4; ++i) {
                    if (pend & (1u << i)) {
                        pv[i] = ld_agent(pslot + (q * 4 + i) * 512 + ccl);
                        if (((unsigned)pv[i] >> 16) != ptag) np |= 1u << i;
                    }
                }
                pend = np;
                if (++guard > 2000000) break;
            }

            int* wslot = hG + (t & 3) * SLOTD;
            const unsigned tagw = (unsigned)(t + 1) << 16;
#pragma unroll
            for (int i = 0; i < 4; ++i) {
                _Float16 p16 = __builtin_bit_cast(_Float16, (unsigned short)(pv[i] & 0xFFFF));
                float v = fast_tanh(a0[i] + a1[i] + (float)p16);
                out1[((size_t)(g * 16 + q * 4 + i) * kT + t) * kH + ccl] = v;
                unsigned hb = (unsigned)__builtin_bit_cast(unsigned short, (_Float16)v);
                st_agent(wslot + (q * 4 + i) * 512 + ccl, (int)(tagw | hb));
            }
            if (lane == 0) st_agent((int*)sent + 128 + g * 32 + j * 4 + w, t + 1);
        }
    }
}

__global__ void finalize_kernel(const int* __restrict__ out0m,
                                const int* __restrict__ h1m,
                                float* __restrict__ out) {
    int idx = blockIdx.x * blockDim.x + threadIdx.x;   // 0..65535
    int lay = idx >> 15;
    int e = idx & 32767;
    int b = e >> 9, col = e & 511;
    int g = b >> 4, row = b & 15;
    const int* src = (lay ? h1m : out0m) + (size_t)g * GRPD + 3 * SLOTD + row * 512 + col;
    unsigned short hb = (unsigned short)((unsigned)*src & 0xFFFFu);
    out[(size_t)kB * kT * kH + idx] = (float)__builtin_bit_cast(_Float16, hb);
}

extern "C" void kernel_launch(void* const* d_in, const int* in_sizes, int n_in,
                              void* d_out, int out_size, void* d_ws, size_t ws_size,
                              hipStream_t stream) {
    const float* x    = (const float*)d_in[0];
    const float* h0in = (const float*)d_in[1];
    const float* wih0 = (const float*)d_in[2];
    const float* whh0 = (const float*)d_in[3];
    const float* bih0 = (const float*)d_in[4];
    const float* bhh0 = (const float*)d_in[5];
    const float* wih1 = (const float*)d_in[6];
    const float* whh1 = (const float*)d_in[7];
    const float* bih1 = (const float*)d_in[8];
    const float* bhh1 = (const float*)d_in[9];
    float* out = (float*)d_out;
    char* ws = (char*)d_ws;

    _Float16* x16 = (_Float16*)(ws + X16_B);
    int* out0m = (int*)(ws + OUT0_B);
    int* p1m   = (int*)(ws + P1_B);
    int* h1m   = (int*)(ws + H1_B);
    int* sent  = (int*)(ws + SENT_B);

    cvt_x_kernel<<<1024, 256, 0, stream>>>(x, x16);
    setup_kernel<<<256, 256, 0, stream>>>(h0in, out0m, h1m, sent);
    scan_kernel<<<96, 256, 0, stream>>>(x16, out0m, p1m, h1m, sent, out,
                                        wih0, whh0, bih0, bhh0, wih1, whh1, bih1, bhh1);
    finalize_kernel<<<256, 256, 0, stream>>>(out0m, h1m, out);
}